// Round 6
// baseline (410.491 us; speedup 1.0000x reference)
//
#include <hip/hip_runtime.h>
#include <stdint.h>

typedef unsigned short u16;
typedef __bf16 bf16x8 __attribute__((ext_vector_type(8)));
typedef float f32x4 __attribute__((ext_vector_type(4)));

#define SCALE_QK 0.125f

__device__ __forceinline__ u16 f2bf(float f) {
    uint32_t u = __builtin_bit_cast(uint32_t, f);
    u += 0x7FFFu + ((u >> 16) & 1u);
    return (u16)(u >> 16);
}

__device__ __forceinline__ int bdiv(int x, int S) {
    return (S == 512) ? (x >> 9) : (int)(((uint64_t)(x >> 6) * 954437177ull) >> 33);
}

__device__ __forceinline__ void gload_lds16(const void* g, void* l) {
    __builtin_amdgcn_global_load_lds(
        (__attribute__((address_space(1))) void*)(g),
        (__attribute__((address_space(3))) void*)(l), 16, 0, 0);
}

// ---------------- f32 -> bf16 converts ----------------
__global__ void cvt_f32_bf16(const float* __restrict__ src, u16* __restrict__ dst, int n4) {
    int i = blockIdx.x * blockDim.x + threadIdx.x;
    if (i >= n4) return;
    float4 v = ((const float4*)src)[i];
    ushort4 o;
    o.x = f2bf(v.x); o.y = f2bf(v.y); o.z = f2bf(v.z); o.w = f2bf(v.w);
    ((ushort4*)dst)[i] = o;
}

struct Ptr8 { const float* p[8]; };

__global__ void cvt_w8(Ptr8 srcs, u16* __restrict__ dst) {
    int i = blockIdx.x * blockDim.x + threadIdx.x;
    int mat = i >> 18, off = i & 262143;
    float4 v = ((const float4*)srcs.p[mat])[off];
    ushort4 o;
    o.x = f2bf(v.x); o.y = f2bf(v.y); o.z = f2bf(v.z); o.w = f2bf(v.w);
    ((ushort4*)(dst + ((size_t)mat << 20)))[off] = o;
}

__global__ void prep(const int* __restrict__ maski, float* __restrict__ mb,
                     const float* __restrict__ bqt, const float* __restrict__ bkt,
                     const float* __restrict__ bqi, const float* __restrict__ bki,
                     float* __restrict__ biasbuf) {
    int i = blockIdx.x * blockDim.x + threadIdx.x;
    if (i < 8192) {
        int v0 = maski[0];
        int v = (v0 == 0x01010101) ? (int)((const unsigned char*)maski)[i] : maski[i];
        mb[i] = v ? 0.0f : -1e30f;
    } else if (i < 12288) {
        int j = i - 8192;
        float v = (j < 1024) ? bqt[j] : (j < 2048) ? bkt[j - 1024]
                : (j < 3072) ? bqi[j - 2048] : bki[j - 3072];
        biasbuf[j] = v;
    }
}

// ---------------- 256x256x64 8-wave deep-pipelined GEMM (fused pair) ----------------
// C = A[M,1024] * Bt[N,1024]^T + bias. Two independent problem sets concatenated
// in one grid. LAYOUT 0: f32 [M][1024]. LAYOUT 1: bf16 head-split QK. LAYOUT 2: bf16 Vt.
template<int LAYOUT>
__global__ __launch_bounds__(512)
void gemm256(const u16* __restrict__ A0, const u16* __restrict__ B0,
             const float* __restrict__ bias0, void* __restrict__ C0,
             int nx0, int S0, size_t pstr0, int nblk0,
             const u16* __restrict__ A1, const u16* __restrict__ B1,
             const float* __restrict__ bias1, void* __restrict__ C1,
             int nx1, int S1, size_t pstr1) {
    constexpr int K = 1024;
    constexpr int NT = K / 64;        // 16 K-tiles
    __shared__ u16 As[2][256 * 64];   // 2 x 32 KiB
    __shared__ u16 Bs[2][256 * 64];
    const int tid = threadIdx.x;
    const int wid = tid >> 6, lane = tid & 63;
    const int lo = lane & 15, hi = lane >> 4;
    const int wm = wid >> 2, wn = wid & 3;
    const int tot = (int)gridDim.x;
    int f = ((int)blockIdx.x & 7) * (tot >> 3) + ((int)blockIdx.x >> 3);
    const u16 *Ag, *Bg; const float* bias; void* Cg; int nx, S; size_t pstr;
    if (f < nblk0) { Ag = A0; Bg = B0; bias = bias0; Cg = C0; nx = nx0; S = S0; pstr = pstr0; }
    else { f -= nblk0; Ag = A1; Bg = B1; bias = bias1; Cg = C1; nx = nx1; S = S1; pstr = pstr1; }
    const int bm = f / nx, bn = f - bm * nx;
    const u16* Ab = Ag + (size_t)bm * 256 * K;
    const u16* Bb = Bg + (size_t)bn * 256 * K;

    // staging: chunk = 64 rows x 128 B = 4096 u16 elements; thread t covers
    // 16B slot t. XOR involution: LDS slot s of row r holds global slot s^(r&7).
    const int srow = tid >> 3;
    const int sslot = (tid & 7) ^ (srow & 7);
    const int ldst = (tid >> 6) * 512;          // wave-uniform LDS base (elements)

    auto stageA = [&](int buf, int k0, int c) {
        gload_lds16(Ab + (size_t)(c * 64 + srow) * K + k0 + sslot * 8,
                    &As[buf][0] + c * 4096 + ldst);
    };
    auto stageB = [&](int buf, int k0, int c) {
        gload_lds16(Bb + (size_t)(c * 64 + srow) * K + k0 + sslot * 8,
                    &Bs[buf][0] + c * 4096 + ldst);
    };

    f32x4 acc[8][4] = {};

#pragma unroll
    for (int c = 0; c < 4; ++c) { stageA(0, 0, c); stageB(0, 0, c); }
    asm volatile("s_waitcnt vmcnt(0)" ::: "memory");
    __builtin_amdgcn_s_barrier();

    for (int t = 0; t < NT; ++t) {
        const int cur = t & 1;
        const int k0n = (t + 1) * 64;
        const u16* Atile = &As[cur][0];
        const u16* Btile = &Bs[cur][0];
#pragma unroll
        for (int ph = 0; ph < 4; ++ph) {
            const int ks = ph >> 1, mh = ph & 1;
            bf16x8 af[4], bq[4];
#pragma unroll
            for (int m = 0; m < 4; ++m) {
                int row = wm * 128 + mh * 64 + m * 16 + lo;
                af[m] = *(const bf16x8*)(Atile + row * 64 + (((ks * 4 + hi) ^ (row & 7)) << 3));
            }
#pragma unroll
            for (int n = 0; n < 4; ++n) {
                int row = wn * 64 + n * 16 + lo;
                bq[n] = *(const bf16x8*)(Btile + row * 64 + (((ks * 4 + hi) ^ (row & 7)) << 3));
            }
            if (t + 1 < NT) {
                if (ph == 0) {
#pragma unroll
                    for (int c = 0; c < 4; ++c) stageA(cur ^ 1, k0n, c);
                } else if (ph == 1) {
#pragma unroll
                    for (int c = 0; c < 4; ++c) stageB(cur ^ 1, k0n, c);
                }
            }
            __builtin_amdgcn_s_barrier();
            __builtin_amdgcn_s_setprio(1);
#pragma unroll
            for (int m = 0; m < 4; ++m)
#pragma unroll
                for (int n = 0; n < 4; ++n)
                    acc[mh * 4 + m][n] =
                        __builtin_amdgcn_mfma_f32_16x16x32_bf16(af[m], bq[n], acc[mh * 4 + m][n], 0, 0, 0);
            __builtin_amdgcn_s_setprio(0);
            if (ph < 3) {
                __builtin_amdgcn_s_barrier();
            } else {
                asm volatile("s_waitcnt vmcnt(0)" ::: "memory");
                __builtin_amdgcn_s_barrier();
            }
        }
    }

    const int rowbase = bm * 256 + wm * 128, colbase = bn * 256 + wn * 64;

    if (LAYOUT == 0) {
        float* C = (float*)Cg;
#pragma unroll
        for (int m = 0; m < 8; ++m)
#pragma unroll
            for (int r = 0; r < 4; ++r) {
                int row = rowbase + m * 16 + hi * 4 + r;
#pragma unroll
                for (int n = 0; n < 4; ++n) {
                    int col = colbase + n * 16 + lo;
                    C[(size_t)row * 1024 + col] = acc[m][n][r] + bias[col];
                }
            }
    } else if (LAYOUT == 1) {
#pragma unroll
        for (int m = 0; m < 8; ++m)
#pragma unroll
            for (int r = 0; r < 4; ++r) {
                int row = rowbase + m * 16 + hi * 4 + r;
                int b = bdiv(row, S);
                int s = row - b * S;
#pragma unroll
                for (int n = 0; n < 4; ++n) {
                    int cb = colbase + n * 16;
                    int part = cb >> 10, h = (cb >> 6) & 15;
                    u16* bp = (u16*)Cg + (size_t)part * pstr +
                              (((size_t)(b * 16 + h) * S + s) << 6) + (cb & 63) + lo;
                    *bp = f2bf(acc[m][n][r] + bias[cb + lo]);
                }
            }
    } else {
        u16* base = (u16*)Cg;
        int bn_[4], s0_[4];
#pragma unroll
        for (int n = 0; n < 4; ++n) {
            int col0 = colbase + n * 16;
            int b = bdiv(col0, S);
            bn_[n] = b;
            s0_[n] = col0 - b * S;
        }
#pragma unroll
        for (int m = 0; m < 8; ++m)
#pragma unroll
            for (int r = 0; r < 4; ++r) {
                int dout = rowbase + m * 16 + hi * 4 + r;   // 0..1023
                float bv = bias[dout];
#pragma unroll
                for (int n = 0; n < 4; ++n)
                    base[((size_t)bn_[n] * 1024 + dout) * S + s0_[n] + lo] =
                        f2bf(acc[m][n][r] + bv);
            }
    }
}

// ---------------- fused flash attention v4 (unchanged from R4) ----------------
template<int MASKED, int NQ, int SK>
__global__ __launch_bounds__(256)
void attn_v4(const u16* __restrict__ Q, const u16* __restrict__ Kb,
             const u16* __restrict__ Vt, const float* __restrict__ mb,
             u16* __restrict__ Out) {
    constexpr int SQ = NQ * 64;
    constexpr int NC = SK / 64;
    __shared__ u16 kls[2][64 * 64];
    __shared__ u16 vls[2][64 * 64];
    __shared__ u16 pls[4][16 * 72];
    const int tid = threadIdx.x, wid = tid >> 6, lane = tid & 63;
    const int lo = lane & 15, hi = lane >> 4;
    const int id = blockIdx.x;
    const int f = (id & 7) * (NQ * 32) + (id >> 3);
    const int qc = f % NQ, bh = f / NQ;
    const int b = bh >> 4, h = bh & 15;
    const int q0 = qc * 64 + wid * 16;
    const u16* Qp = Q + ((size_t)bh * SQ + q0) * 64;
    const u16* Kp = Kb + (size_t)bh * SK * 64;
    const u16* Vp = Vt + (size_t)bh * 64 * SK;

    bf16x8 qf[2];
#pragma unroll
    for (int ks = 0; ks < 2; ++ks)
        qf[ks] = *(const bf16x8*)(Qp + lo * 64 + ks * 32 + hi * 8);

    f32x4 oacc[4] = {};
    float m = -3e38f, l = 0.f;
    u16* pl = pls[wid];
    uint32_t* pl32 = (uint32_t*)pl;

    auto stage = [&](int bufi, int c0) {
#pragma unroll
        for (int j = 0; j < 2; ++j) {
            const int beta = (j * 4 + wid) * 64 + lane;
            const int row = beta >> 3, slot = beta & 7;
            const int e = (slot ^ (row & 7)) << 3;
            gload_lds16(Kp + (size_t)(c0 + row) * 64 + e,
                        &kls[bufi][0] + (j * 4 + wid) * 512);
            gload_lds16(Vp + (size_t)row * SK + c0 + e,
                        &vls[bufi][0] + (j * 4 + wid) * 512);
        }
    };

    stage(0, 0);
    __syncthreads();

    for (int c = 0; c < NC; ++c) {
        const int c0 = c * 64;
        if (c + 1 < NC) stage((c + 1) & 1, c0 + 64);
        const u16* kb = &kls[c & 1][0];
        const u16* vb = &vls[c & 1][0];

        float sc[4][4];
#pragma unroll
        for (int kt = 0; kt < 4; ++kt) {
            const int krow = kt * 16 + lo;
            const int rx = krow & 7;
            bf16x8 kf0 = *(const bf16x8*)(kb + krow * 64 + ((hi ^ rx) << 3));
            bf16x8 kf1 = *(const bf16x8*)(kb + krow * 64 + (((4 + hi) ^ rx) << 3));
            f32x4 z = {};
            __builtin_amdgcn_s_setprio(1);
            z = __builtin_amdgcn_mfma_f32_16x16x32_bf16(kf0, qf[0], z, 0, 0, 0);
            z = __builtin_amdgcn_mfma_f32_16x16x32_bf16(kf1, qf[1], z, 0, 0, 0);
            __builtin_amdgcn_s_setprio(0);
            if (MASKED) {
                float4 mv = *(const float4*)(mb + b * SK + c0 + kt * 16 + hi * 4);
#pragma unroll
                for (int r = 0; r < 4; ++r) sc[kt][r] = z[r] * SCALE_QK + ((const float*)&mv)[r];
            } else {
#pragma unroll
                for (int r = 0; r < 4; ++r) sc[kt][r] = z[r] * SCALE_QK;
            }
        }
        float a0 = fmaxf(fmaxf(sc[0][0], sc[0][1]), fmaxf(sc[0][2], sc[0][3]));
        float a1 = fmaxf(fmaxf(sc[1][0], sc[1][1]), fmaxf(sc[1][2], sc[1][3]));
        float a2 = fmaxf(fmaxf(sc[2][0], sc[2][1]), fmaxf(sc[2][2], sc[2][3]));
        float a3 = fmaxf(fmaxf(sc[3][0], sc[3][1]), fmaxf(sc[3][2], sc[3][3]));
        float pmax = fmaxf(fmaxf(a0, a1), fmaxf(a2, a3));
        pmax = fmaxf(pmax, __shfl_xor(pmax, 16));
        pmax = fmaxf(pmax, __shfl_xor(pmax, 32));
        if (!__all(pmax - m <= 8.0f)) {
            float mn = fmaxf(m, pmax);
            float alpha = __expf(m - mn);
            m = mn;
            l *= alpha;
#pragma unroll
            for (int n = 0; n < 4; ++n)
#pragma unroll
                for (int r = 0; r < 4; ++r) oacc[n][r] *= alpha;
        }
        float sum = 0.f;
#pragma unroll
        for (int kt = 0; kt < 4; ++kt) {
#pragma unroll
            for (int r = 0; r < 4; ++r) {
                float p = __expf(sc[kt][r] - m);
                sc[kt][r] = p;
                sum += p;
            }
        }
        sum += __shfl_xor(sum, 16);
        sum += __shfl_xor(sum, 32);
        l += sum;
#pragma unroll
        for (int kt = 0; kt < 4; ++kt) {
#pragma unroll
            for (int rp = 0; rp < 2; ++rp) {
                uint32_t w = (uint32_t)f2bf(sc[kt][2 * rp]) |
                             ((uint32_t)f2bf(sc[kt][2 * rp + 1]) << 16);
                pl32[lo * 36 + kt * 8 + hi * 2 + rp] = w;
            }
        }
        bf16x8 pf0 = *(const bf16x8*)(pl + lo * 72 + hi * 8);
        bf16x8 pf1 = *(const bf16x8*)(pl + lo * 72 + 32 + hi * 8);
        __builtin_amdgcn_s_setprio(1);
#pragma unroll
        for (int n = 0; n < 4; ++n) {
            const int d = n * 16 + lo;
            const int dx = d & 7;
            bf16x8 v0 = *(const bf16x8*)(vb + d * 64 + ((hi ^ dx) << 3));
            bf16x8 v1 = *(const bf16x8*)(vb + d * 64 + (((4 + hi) ^ dx) << 3));
            oacc[n] = __builtin_amdgcn_mfma_f32_16x16x32_bf16(v0, pf0, oacc[n], 0, 0, 0);
            oacc[n] = __builtin_amdgcn_mfma_f32_16x16x32_bf16(v1, pf1, oacc[n], 0, 0, 0);
        }
        __builtin_amdgcn_s_setprio(0);
        __syncthreads();
    }
    const float inv = 1.0f / l;
    u16* op = Out + ((size_t)(b * SQ + q0 + lo)) * 1024 + h * 64;
#pragma unroll
    for (int n = 0; n < 4; ++n) {
        ushort4 w;
        w.x = f2bf(oacc[n][0] * inv);
        w.y = f2bf(oacc[n][1] * inv);
        w.z = f2bf(oacc[n][2] * inv);
        w.w = f2bf(oacc[n][3] * inv);
        *(ushort4*)(op + n * 16 + hi * 4) = w;
    }
}

// ---------------- host ----------------
extern "C" void kernel_launch(void* const* d_in, const int* in_sizes, int n_in,
                              void* d_out, int out_size, void* d_ws, size_t ws_size,
                              hipStream_t stream) {
    (void)in_sizes; (void)n_in; (void)out_size; (void)ws_size;
    const float* text  = (const float*)d_in[0];
    const float* image = (const float*)d_in[1];
    const int*   maski = (const int*)d_in[2];
    const float* w_qt = (const float*)d_in[3];  const float* b_qt = (const float*)d_in[4];
    const float* w_ki = (const float*)d_in[5];  const float* b_ki = (const float*)d_in[6];
    const float* w_vi = (const float*)d_in[7];  const float* b_vi = (const float*)d_in[8];
    const float* w_qi = (const float*)d_in[9];  const float* b_qi = (const float*)d_in[10];
    const float* w_kt = (const float*)d_in[11]; const float* b_kt = (const float*)d_in[12];
    const float* w_vt = (const float*)d_in[13]; const float* b_vt = (const float*)d_in[14];
    const float* w_ot = (const float*)d_in[15]; const float* b_ot = (const float*)d_in[16];
    const float* w_oi = (const float*)d_in[17]; const float* b_oi = (const float*)d_in[18];

    const int B = 16, T = 512, P = 576, D = 1024;
    const int MT = B * T;   // 8192
    const int MI = B * P;   // 9216
    const size_t M1 = 1 << 20;

    char* wp = (char*)d_ws;
    auto alloc = [&](size_t bytes) { char* r = wp; wp += (bytes + 255) & ~(size_t)255; return r; };
    u16* Xt   = (u16*)alloc((size_t)MT * D * 2);     // reused as AttT
    u16* Xi   = (u16*)alloc((size_t)MI * D * 2);     // reused as AttI
    u16* Wall = (u16*)alloc(8 * M1 * 2);             // [qt,kt,qi,ki,vt,vi,ot,oi]
    float* biasbuf = (float*)alloc(4096 * 4);        // [b_qt,b_kt,b_qi,b_ki]
    float* mbf  = (float*)alloc((size_t)B * T * 4);
    u16* QKt  = (u16*)alloc((size_t)2 * MT * D * 2); // Q_t | K_t head-split
    u16* QKi  = (u16*)alloc((size_t)2 * MI * D * 2); // Q_i | K_i
    u16* Vtt  = (u16*)alloc((size_t)MT * D * 2);     // [B][16][64][512]
    u16* Vti  = (u16*)alloc((size_t)MI * D * 2);     // [B][16][64][576]

    const u16* Wqk_t = Wall;
    const u16* Wqk_i = Wall + 2 * M1;
    const u16* Wv_t  = Wall + 4 * M1;
    const u16* Wv_i  = Wall + 5 * M1;
    const u16* Wot   = Wall + 6 * M1;
    const u16* Woi   = Wall + 7 * M1;

    cvt_f32_bf16<<<(MT * D / 4) / 256, 256, 0, stream>>>(text, Xt, MT * D / 4);
    cvt_f32_bf16<<<(MI * D / 4) / 256, 256, 0, stream>>>(image, Xi, MI * D / 4);
    Ptr8 w8 = {{w_qt, w_kt, w_qi, w_ki, w_vt, w_vi, w_ot, w_oi}};
    cvt_w8<<<8192, 256, 0, stream>>>(w8, Wall);
    prep<<<48, 256, 0, stream>>>(maski, mbf, b_qt, b_kt, b_qi, b_ki, biasbuf);

    // QKV projections (text + image fused): N=2048, head-split out
    gemm256<1><<<544, 512, 0, stream>>>(
        Xt, Wqk_t, biasbuf,        QKt, 8, T, (size_t)MT * D, 256,
        Xi, Wqk_i, biasbuf + 2048, QKi, 8, P, (size_t)MI * D);
    // V projections (swapped; text + image fused): Vt out
    gemm256<2><<<272, 512, 0, stream>>>(
        Wv_t, Xt, b_vt, Vtt, 32, T, 0, 128,
        Wv_i, Xi, b_vi, Vti, 36, P, 0);

    // attention
    attn_v4<0, 8, 576><<<8 * 256, 256, 0, stream>>>(
        QKt, QKi + (size_t)MI * D, Vti, nullptr, Xt);
    attn_v4<1, 9, 512><<<9 * 256, 256, 0, stream>>>(
        QKi, QKt + (size_t)MT * D, Vtt, mbf, Xi);

    // output projections (text + image fused): f32 out
    gemm256<0><<<272, 512, 0, stream>>>(
        Xt, Wot, b_ot, d_out, 4, T, 0, 128,
        Xi, Woi, b_oi, (void*)((float*)d_out + (size_t)MT * D), 4, P, 0);
}

// Round 7
// 358.334 us; speedup vs baseline: 1.1456x; 1.1456x over previous
//
#include <hip/hip_runtime.h>
#include <stdint.h>

typedef unsigned short u16;
typedef __bf16 bf16x8 __attribute__((ext_vector_type(8)));
typedef float f32x4 __attribute__((ext_vector_type(4)));

#define SCALE_QK 0.125f

__device__ __forceinline__ u16 f2bf(float f) {
    uint32_t u = __builtin_bit_cast(uint32_t, f);
    u += 0x7FFFu + ((u >> 16) & 1u);
    return (u16)(u >> 16);
}

__device__ __forceinline__ int bdiv(int x, int S) {
    return (S == 512) ? (x >> 9) : (int)(((uint64_t)(x >> 6) * 954437177ull) >> 33);
}

__device__ __forceinline__ void gload16(const void* g, void* l) {
    __builtin_amdgcn_global_load_lds(
        (__attribute__((address_space(1))) void*)(g),
        (__attribute__((address_space(3))) void*)(l), 16, 0, 0);
}

template<int W>
__device__ __forceinline__ void vwait() {
    asm volatile("s_waitcnt vmcnt(%0)" :: "n"(W) : "memory");
}

// ---------------- f32 -> bf16 converts ----------------
__global__ void cvt_f32_bf16(const float* __restrict__ src, u16* __restrict__ dst, int n4) {
    int i = blockIdx.x * blockDim.x + threadIdx.x;
    if (i >= n4) return;
    float4 v = ((const float4*)src)[i];
    ushort4 o;
    o.x = f2bf(v.x); o.y = f2bf(v.y); o.z = f2bf(v.z); o.w = f2bf(v.w);
    ((ushort4*)dst)[i] = o;
}

struct Ptr8 { const float* p[8]; };

__global__ void cvt_w8(Ptr8 srcs, u16* __restrict__ dst) {
    int i = blockIdx.x * blockDim.x + threadIdx.x;
    int mat = i >> 18, off = i & 262143;
    float4 v = ((const float4*)srcs.p[mat])[off];
    ushort4 o;
    o.x = f2bf(v.x); o.y = f2bf(v.y); o.z = f2bf(v.z); o.w = f2bf(v.w);
    ((ushort4*)(dst + ((size_t)mat << 20)))[off] = o;
}

__global__ void prep(const int* __restrict__ maski, float* __restrict__ mb,
                     const float* __restrict__ bqt, const float* __restrict__ bkt,
                     const float* __restrict__ bqi, const float* __restrict__ bki,
                     float* __restrict__ biasbuf) {
    int i = blockIdx.x * blockDim.x + threadIdx.x;
    if (i < 8192) {
        int v0 = maski[0];
        int v = (v0 == 0x01010101) ? (int)((const unsigned char*)maski)[i] : maski[i];
        mb[i] = v ? 0.0f : -1e30f;
    } else if (i < 12288) {
        int j = i - 8192;
        float v = (j < 1024) ? bqt[j] : (j < 2048) ? bkt[j - 1024]
                : (j < 3072) ? bqi[j - 2048] : bki[j - 3072];
        biasbuf[j] = v;
    }
}

// ---------------- 256x256 GEMM, 32-phase counted-vmcnt pipeline ----------------
// Unit = K-slice of 32 cols for A AND B interleaved in one 32 KB region:
// [256 rows][8 slots x 16B], slots 0-3 = A, 4-7 = B, XOR slot^(row&7).
// 4 regions rotate; stage unit u+3 at phase u; steady-state vmcnt(8) (T4).
struct Seg {
    const u16* A; const u16* B; const float* bias; void* C;
    int nx, S, layout, end; size_t pstr;
};
struct Segs { Seg s[4]; };

__global__ __launch_bounds__(512, 2)
void gemm256v2(Segs segs) {
    constexpr int K = 1024;
    __shared__ u16 U[4][256 * 64];    // 128 KiB
    const int tid = threadIdx.x;
    const int wid = tid >> 6, lane = tid & 63;
    const int lo = lane & 15, hi = lane >> 4;
    const int wm = wid >> 2, wn = wid & 3;
    const int tot = (int)gridDim.x;
    int f = ((int)blockIdx.x & 7) * (tot >> 3) + ((int)blockIdx.x >> 3);
    int si = 0;
    while (si < 3 && f >= segs.s[si].end) ++si;
    if (si > 0) f -= segs.s[si - 1].end;
    const Seg sg = segs.s[si];
    const int bm = f / sg.nx, bn = f - bm * sg.nx;
    const u16* Ab = sg.A + (size_t)bm * 256 * K;
    const u16* Bb = sg.B + (size_t)bn * 256 * K;

    const int srow8 = tid >> 3;
    const int sslot = tid & 7;

    auto stage_unit = [&](int u) {
        const int reg = u & 3;
        const int kb = u * 32;
#pragma unroll
        for (int c = 0; c < 4; ++c) {
            int row = c * 64 + srow8;
            int ss = sslot ^ (row & 7);
            const u16* src = (ss < 4)
                ? Ab + (size_t)row * K + kb + ss * 8
                : Bb + (size_t)row * K + kb + (ss - 4) * 8;
            gload16(src, &U[reg][0] + c * 4096 + wid * 512);
        }
    };

    f32x4 acc[8][4] = {};

    stage_unit(0); stage_unit(1); stage_unit(2);

    auto phase = [&](int u, bool doStage) {
        const u16* R = &U[u & 3][0];
        bf16x8 af[8], bq[4];
#pragma unroll
        for (int m = 0; m < 8; ++m) {
            int row = wm * 128 + m * 16 + lo;
            af[m] = *(const bf16x8*)(R + row * 64 + ((hi ^ (row & 7)) << 3));
        }
#pragma unroll
        for (int n = 0; n < 4; ++n) {
            int row = wn * 64 + n * 16 + lo;
            bq[n] = *(const bf16x8*)(R + row * 64 + (((4 + hi) ^ (row & 7)) << 3));
        }
        if (doStage) stage_unit(u + 3);
        __builtin_amdgcn_s_setprio(1);
#pragma unroll
        for (int m = 0; m < 8; ++m)
#pragma unroll
            for (int n = 0; n < 4; ++n)
                acc[m][n] = __builtin_amdgcn_mfma_f32_16x16x32_bf16(af[m], bq[n], acc[m][n], 0, 0, 0);
        __builtin_amdgcn_s_setprio(0);
    };

#pragma unroll 4
    for (int u = 0; u < 28; ++u) {
        vwait<8>();
        __builtin_amdgcn_s_barrier();
        phase(u, true);
    }
    vwait<8>(); __builtin_amdgcn_s_barrier(); phase(28, true);   // stages unit 31
    vwait<8>(); __builtin_amdgcn_s_barrier(); phase(29, false);
    vwait<4>(); __builtin_amdgcn_s_barrier(); phase(30, false);
    vwait<0>(); __builtin_amdgcn_s_barrier(); phase(31, false);

    const int rowbase = bm * 256 + wm * 128, colbase = bn * 256 + wn * 64;

    if (sg.layout == 0) {
        float* C = (float*)sg.C;
#pragma unroll
        for (int m = 0; m < 8; ++m)
#pragma unroll
            for (int r = 0; r < 4; ++r) {
                int row = rowbase + m * 16 + hi * 4 + r;
#pragma unroll
                for (int n = 0; n < 4; ++n) {
                    int col = colbase + n * 16 + lo;
                    C[(size_t)row * 1024 + col] = acc[m][n][r] + sg.bias[col];
                }
            }
    } else if (sg.layout == 1) {
#pragma unroll
        for (int m = 0; m < 8; ++m)
#pragma unroll
            for (int r = 0; r < 4; ++r) {
                int row = rowbase + m * 16 + hi * 4 + r;
                int b = bdiv(row, sg.S);
                int s = row - b * sg.S;
#pragma unroll
                for (int n = 0; n < 4; ++n) {
                    int cb = colbase + n * 16;
                    int part = cb >> 10, h = (cb >> 6) & 15;
                    u16* bp = (u16*)sg.C + (size_t)part * sg.pstr +
                              (((size_t)(b * 16 + h) * sg.S + s) << 6) + (cb & 63) + lo;
                    *bp = f2bf(acc[m][n][r] + sg.bias[cb + lo]);
                }
            }
    } else {
        u16* base = (u16*)sg.C;
        int bn_[4], s0_[4];
#pragma unroll
        for (int n = 0; n < 4; ++n) {
            int col0 = colbase + n * 16;
            int b = bdiv(col0, sg.S);
            bn_[n] = b;
            s0_[n] = col0 - b * sg.S;
        }
#pragma unroll
        for (int m = 0; m < 8; ++m)
#pragma unroll
            for (int r = 0; r < 4; ++r) {
                int dout = rowbase + m * 16 + hi * 4 + r;   // 0..1023
                float bv = sg.bias[dout];
#pragma unroll
                for (int n = 0; n < 4; ++n)
                    base[((size_t)bn_[n] * 1024 + dout) * sg.S + s0_[n] + lo] =
                        f2bf(acc[m][n][r] + bv);
            }
    }
}

// ---------------- fused flash attention v4 (unchanged, passing) ----------------
template<int MASKED, int NQ, int SK>
__global__ __launch_bounds__(256)
void attn_v4(const u16* __restrict__ Q, const u16* __restrict__ Kb,
             const u16* __restrict__ Vt, const float* __restrict__ mb,
             u16* __restrict__ Out) {
    constexpr int SQ = NQ * 64;
    constexpr int NC = SK / 64;
    __shared__ u16 kls[2][64 * 64];
    __shared__ u16 vls[2][64 * 64];
    __shared__ u16 pls[4][16 * 72];
    const int tid = threadIdx.x, wid = tid >> 6, lane = tid & 63;
    const int lo = lane & 15, hi = lane >> 4;
    const int id = blockIdx.x;
    const int f = (id & 7) * (NQ * 32) + (id >> 3);
    const int qc = f % NQ, bh = f / NQ;
    const int b = bh >> 4, h = bh & 15;
    const int q0 = qc * 64 + wid * 16;
    const u16* Qp = Q + ((size_t)bh * SQ + q0) * 64;
    const u16* Kp = Kb + (size_t)bh * SK * 64;
    const u16* Vp = Vt + (size_t)bh * 64 * SK;

    bf16x8 qf[2];
#pragma unroll
    for (int ks = 0; ks < 2; ++ks)
        qf[ks] = *(const bf16x8*)(Qp + lo * 64 + ks * 32 + hi * 8);

    f32x4 oacc[4] = {};
    float m = -3e38f, l = 0.f;
    u16* pl = pls[wid];
    uint32_t* pl32 = (uint32_t*)pl;

    auto stage = [&](int bufi, int c0) {
#pragma unroll
        for (int j = 0; j < 2; ++j) {
            const int beta = (j * 4 + wid) * 64 + lane;
            const int row = beta >> 3, slot = beta & 7;
            const int e = (slot ^ (row & 7)) << 3;
            gload16(Kp + (size_t)(c0 + row) * 64 + e,
                    &kls[bufi][0] + (j * 4 + wid) * 512);
            gload16(Vp + (size_t)row * SK + c0 + e,
                    &vls[bufi][0] + (j * 4 + wid) * 512);
        }
    };

    stage(0, 0);
    __syncthreads();

    for (int c = 0; c < NC; ++c) {
        const int c0 = c * 64;
        if (c + 1 < NC) stage((c + 1) & 1, c0 + 64);
        const u16* kb = &kls[c & 1][0];
        const u16* vb = &vls[c & 1][0];

        float sc[4][4];
#pragma unroll
        for (int kt = 0; kt < 4; ++kt) {
            const int krow = kt * 16 + lo;
            const int rx = krow & 7;
            bf16x8 kf0 = *(const bf16x8*)(kb + krow * 64 + ((hi ^ rx) << 3));
            bf16x8 kf1 = *(const bf16x8*)(kb + krow * 64 + (((4 + hi) ^ rx) << 3));
            f32x4 z = {};
            __builtin_amdgcn_s_setprio(1);
            z = __builtin_amdgcn_mfma_f32_16x16x32_bf16(kf0, qf[0], z, 0, 0, 0);
            z = __builtin_amdgcn_mfma_f32_16x16x32_bf16(kf1, qf[1], z, 0, 0, 0);
            __builtin_amdgcn_s_setprio(0);
            if (MASKED) {
                float4 mv = *(const float4*)(mb + b * SK + c0 + kt * 16 + hi * 4);
#pragma unroll
                for (int r = 0; r < 4; ++r) sc[kt][r] = z[r] * SCALE_QK + ((const float*)&mv)[r];
            } else {
#pragma unroll
                for (int r = 0; r < 4; ++r) sc[kt][r] = z[r] * SCALE_QK;
            }
        }
        float a0 = fmaxf(fmaxf(sc[0][0], sc[0][1]), fmaxf(sc[0][2], sc[0][3]));
        float a1 = fmaxf(fmaxf(sc[1][0], sc[1][1]), fmaxf(sc[1][2], sc[1][3]));
        float a2 = fmaxf(fmaxf(sc[2][0], sc[2][1]), fmaxf(sc[2][2], sc[2][3]));
        float a3 = fmaxf(fmaxf(sc[3][0], sc[3][1]), fmaxf(sc[3][2], sc[3][3]));
        float pmax = fmaxf(fmaxf(a0, a1), fmaxf(a2, a3));
        pmax = fmaxf(pmax, __shfl_xor(pmax, 16));
        pmax = fmaxf(pmax, __shfl_xor(pmax, 32));
        if (!__all(pmax - m <= 8.0f)) {
            float mn = fmaxf(m, pmax);
            float alpha = __expf(m - mn);
            m = mn;
            l *= alpha;
#pragma unroll
            for (int n = 0; n < 4; ++n)
#pragma unroll
                for (int r = 0; r < 4; ++r) oacc[n][r] *= alpha;
        }
        float sum = 0.f;
#pragma unroll
        for (int kt = 0; kt < 4; ++kt) {
#pragma unroll
            for (int r = 0; r < 4; ++r) {
                float p = __expf(sc[kt][r] - m);
                sc[kt][r] = p;
                sum += p;
            }
        }
        sum += __shfl_xor(sum, 16);
        sum += __shfl_xor(sum, 32);
        l += sum;
#pragma unroll
        for (int kt = 0; kt < 4; ++kt) {
#pragma unroll
            for (int rp = 0; rp < 2; ++rp) {
                uint32_t w = (uint32_t)f2bf(sc[kt][2 * rp]) |
                             ((uint32_t)f2bf(sc[kt][2 * rp + 1]) << 16);
                pl32[lo * 36 + kt * 8 + hi * 2 + rp] = w;
            }
        }
        bf16x8 pf0 = *(const bf16x8*)(pl + lo * 72 + hi * 8);
        bf16x8 pf1 = *(const bf16x8*)(pl + lo * 72 + 32 + hi * 8);
        __builtin_amdgcn_s_setprio(1);
#pragma unroll
        for (int n = 0; n < 4; ++n) {
            const int d = n * 16 + lo;
            const int dx = d & 7;
            bf16x8 v0 = *(const bf16x8*)(vb + d * 64 + ((hi ^ dx) << 3));
            bf16x8 v1 = *(const bf16x8*)(vb + d * 64 + (((4 + hi) ^ dx) << 3));
            oacc[n] = __builtin_amdgcn_mfma_f32_16x16x32_bf16(v0, pf0, oacc[n], 0, 0, 0);
            oacc[n] = __builtin_amdgcn_mfma_f32_16x16x32_bf16(v1, pf1, oacc[n], 0, 0, 0);
        }
        __builtin_amdgcn_s_setprio(0);
        __syncthreads();
    }
    const float inv = 1.0f / l;
    u16* op = Out + ((size_t)(b * SQ + q0 + lo)) * 1024 + h * 64;
#pragma unroll
    for (int n = 0; n < 4; ++n) {
        ushort4 w;
        w.x = f2bf(oacc[n][0] * inv);
        w.y = f2bf(oacc[n][1] * inv);
        w.z = f2bf(oacc[n][2] * inv);
        w.w = f2bf(oacc[n][3] * inv);
        *(ushort4*)(op + n * 16 + hi * 4) = w;
    }
}

// ---------------- host ----------------
extern "C" void kernel_launch(void* const* d_in, const int* in_sizes, int n_in,
                              void* d_out, int out_size, void* d_ws, size_t ws_size,
                              hipStream_t stream) {
    (void)in_sizes; (void)n_in; (void)out_size; (void)ws_size;
    const float* text  = (const float*)d_in[0];
    const float* image = (const float*)d_in[1];
    const int*   maski = (const int*)d_in[2];
    const float* w_qt = (const float*)d_in[3];  const float* b_qt = (const float*)d_in[4];
    const float* w_ki = (const float*)d_in[5];  const float* b_ki = (const float*)d_in[6];
    const float* w_vi = (const float*)d_in[7];  const float* b_vi = (const float*)d_in[8];
    const float* w_qi = (const float*)d_in[9];  const float* b_qi = (const float*)d_in[10];
    const float* w_kt = (const float*)d_in[11]; const float* b_kt = (const float*)d_in[12];
    const float* w_vt = (const float*)d_in[13]; const float* b_vt = (const float*)d_in[14];
    const float* w_ot = (const float*)d_in[15]; const float* b_ot = (const float*)d_in[16];
    const float* w_oi = (const float*)d_in[17]; const float* b_oi = (const float*)d_in[18];

    const int B = 16, T = 512, P = 576, D = 1024;
    const int MT = B * T;   // 8192
    const int MI = B * P;   // 9216
    const size_t M1 = 1 << 20;

    char* wp = (char*)d_ws;
    auto alloc = [&](size_t bytes) { char* r = wp; wp += (bytes + 255) & ~(size_t)255; return r; };
    u16* Xt   = (u16*)alloc((size_t)MT * D * 2);     // reused as AttT
    u16* Xi   = (u16*)alloc((size_t)MI * D * 2);     // reused as AttI
    u16* Wall = (u16*)alloc(8 * M1 * 2);             // [qt,kt,qi,ki,vt,vi,ot,oi]
    float* biasbuf = (float*)alloc(4096 * 4);        // [b_qt,b_kt | b_qi,b_ki]
    float* mbf  = (float*)alloc((size_t)B * T * 4);
    u16* QKt  = (u16*)alloc((size_t)2 * MT * D * 2); // Q_t | K_t head-split
    u16* QKi  = (u16*)alloc((size_t)2 * MI * D * 2); // Q_i | K_i
    u16* Vtt  = (u16*)alloc((size_t)MT * D * 2);     // [B][16][64][512]
    u16* Vti  = (u16*)alloc((size_t)MI * D * 2);     // [B][16][64][576]

    const u16* Wqk_t = Wall;
    const u16* Wqk_i = Wall + 2 * M1;
    const u16* Wv_t  = Wall + 4 * M1;
    const u16* Wv_i  = Wall + 5 * M1;
    const u16* Wot   = Wall + 6 * M1;
    const u16* Woi   = Wall + 7 * M1;

    cvt_f32_bf16<<<(MT * D / 4) / 256, 256, 0, stream>>>(text, Xt, MT * D / 4);
    cvt_f32_bf16<<<(MI * D / 4) / 256, 256, 0, stream>>>(image, Xi, MI * D / 4);
    Ptr8 w8 = {{w_qt, w_kt, w_qi, w_ki, w_vt, w_vi, w_ot, w_oi}};
    cvt_w8<<<8192, 256, 0, stream>>>(w8, Wall);
    prep<<<48, 256, 0, stream>>>(maski, mbf, b_qt, b_kt, b_qi, b_ki, biasbuf);

    // QKV-pair + V-pair fused: 256+288+128+144 = 816 blocks
    {
        Segs sgs;
        sgs.s[0] = {Xt,   Wqk_t, biasbuf,        QKt, 8,  512, 1, 256, (size_t)MT * D};
        sgs.s[1] = {Xi,   Wqk_i, biasbuf + 2048, QKi, 8,  576, 1, 544, (size_t)MI * D};
        sgs.s[2] = {Wv_t, Xt,    b_vt,           Vtt, 32, 512, 2, 672, 0};
        sgs.s[3] = {Wv_i, Xi,    b_vi,           Vti, 36, 576, 2, 816, 0};
        gemm256v2<<<816, 512, 0, stream>>>(sgs);
    }

    // attention
    attn_v4<0, 8, 576><<<8 * 256, 256, 0, stream>>>(
        QKt, QKi + (size_t)MI * D, Vti, nullptr, Xt);
    attn_v4<1, 9, 512><<<9 * 256, 256, 0, stream>>>(
        QKi, QKt + (size_t)MT * D, Vtt, mbf, Xi);

    // O-pair fused: 128+144 = 272 blocks, f32 out
    {
        Segs sgs;
        sgs.s[0] = {Xt, Wot, b_ot, d_out, 4, 512, 0, 128, 0};
        sgs.s[1] = {Xi, Woi, b_oi, (void*)((float*)d_out + (size_t)MT * D), 4, 576, 0, 272, 0};
        sgs.s[2] = sgs.s[1]; sgs.s[2].end = 272;
        sgs.s[3] = sgs.s[1]; sgs.s[3].end = 272;
        gemm256v2<<<272, 512, 0, stream>>>(sgs);
    }
}